// Round 4
// baseline (529.434 us; speedup 1.0000x reference)
//
#include <hip/hip_runtime.h>

// ---------------------------------------------------------------------------
// 3-layer GCN (PyG gcn_norm semantics) on MI355X.
//   0. init: zero cnt + detect edge_index storage (int32 vs int64)
//   1. degree count ; scan -> CSR offsets (+dis, +cursor=0) ; fill CSR
//   2. W1 -> split bf16 hi/lo + transpose (Bt[2][64][K])
//   3. H0 = x @ W1 split-bf16 MFMA (xh*Wh + xl*Wh + xh*Wl), K-split x8.
//      BARRIER-FREE: per-wave 64x64 tile, A loaded per-wave from global,
//      converted in-register via v_cvt_pk_bf16_f32, no LDS.
//   4. H1 = relu(Agg(H0)+b1) ; H2 = relu(Agg(H1@W2)+b2)
//   5. out = softmax(Agg(H2@W3)+b3)
// ---------------------------------------------------------------------------

typedef __attribute__((ext_vector_type(8))) short bf16x8;
typedef __attribute__((ext_vector_type(4))) float f32x4;

union PK4 { unsigned u[4]; bf16x8 v; };

__device__ __forceinline__ unsigned cvt_pk_bf16(float a, float b) {
    // D[15:0] = bf16_rne(a), D[31:16] = bf16_rne(b)
    unsigned r;
    asm("v_cvt_pk_bf16_f32 %0, %1, %2" : "=v"(r) : "v"(a), "v"(b));
    return r;
}

__device__ __forceinline__ unsigned short f2bf_rne(float f) {
    unsigned u = __float_as_uint(f);
    unsigned r = (u + 0x7FFFu + ((u >> 16) & 1u)) >> 16;
    return (unsigned short)r;
}

// --- zero cnt; thread 0 probes int64-vs-int32 (int64 < 2^31 -> odd words 0)
__global__ void init_k(const int* __restrict__ ei, int* __restrict__ flag,
                       int* __restrict__ cnt, int n) {
    int t = blockIdx.x * blockDim.x + threadIdx.x;
    if (t < n) cnt[t] = 0;
    if (t == 0) {
        int f = 1;
        for (int i = 0; i < 256; ++i) {
            if (ei[2 * i + 1] != 0) { f = 0; break; }
        }
        *flag = f;
    }
}

__device__ __forceinline__ int edge_val(const int* __restrict__ ei, long long idx, int f64) {
    return f64 ? ei[2 * idx] : ei[(int)idx];
}

__global__ void count_deg_k(const int* __restrict__ ei, int E, const int* __restrict__ flag,
                            int* __restrict__ cnt) {
    int e = blockIdx.x * blockDim.x + threadIdx.x;
    if (e >= E) return;
    int f = *flag;
    int c = edge_val(ei, (long long)E + e, f);
    atomicAdd(&cnt[c], 1);
}

// scan + dis + cursor init, single block
__global__ void scan_k(const int* __restrict__ cnt, int* __restrict__ offs,
                       float* __restrict__ dis, int* __restrict__ cursor, int n) {
    __shared__ int sums[1024];
    const int t = threadIdx.x;
    const int base = t * 16;
    int loc[16];
    int s = 0;
#pragma unroll
    for (int i = 0; i < 16; ++i) {
        loc[i] = s;
        int idx = base + i;
        s += (idx < n) ? cnt[idx] : 0;
    }
    sums[t] = s;
    __syncthreads();
    for (int o = 1; o < 1024; o <<= 1) {
        int v = (t >= o) ? sums[t - o] : 0;
        __syncthreads();
        sums[t] += v;
        __syncthreads();
    }
    int tbase = (t == 0) ? 0 : sums[t - 1];
#pragma unroll
    for (int i = 0; i < 16; ++i) {
        int idx = base + i;
        if (idx < n) {
            offs[idx] = tbase + loc[i];
            cursor[idx] = 0;
            dis[idx] = rsqrtf((float)(cnt[idx] + 1));  // +1: self loop
        }
    }
    if (t == 1023) offs[n] = sums[1023];
}

__global__ void fill_csr_k(const int* __restrict__ ei, int E, const int* __restrict__ flag,
                           const int* __restrict__ offs, int* __restrict__ cursor,
                           const float* __restrict__ dis, int* __restrict__ src,
                           float* __restrict__ w) {
    int e = blockIdx.x * blockDim.x + threadIdx.x;
    if (e >= E) return;
    int f = *flag;
    int r = edge_val(ei, (long long)e, f);
    int c = edge_val(ei, (long long)E + e, f);
    int pos = offs[c] + atomicAdd(&cursor[c], 1);
    src[pos] = r;
    w[pos] = dis[r] * dis[c];
}

// --- W1 [K][64] fp32 -> Bt[2][64][K] bf16 (hi, lo), transposed.
__global__ void prep_w1_k(const float* __restrict__ W1, unsigned short* __restrict__ Bt,
                          int K) {
    int g = blockIdx.x * blockDim.x + threadIdx.x;
    if (g >= K * 64) return;
    int nn = g & 63, k = g >> 6;
    float f = W1[(size_t)k * 64 + nn];
    unsigned short hi = f2bf_rne(f);
    float hf = __uint_as_float((unsigned)hi << 16);
    unsigned short lo = f2bf_rne(f - hf);
    Bt[(size_t)nn * K + k] = hi;
    Bt[(size_t)64 * K + (size_t)nn * K + k] = lo;
}

// --- GEMM1: [n x K] fp32 @ Bt[2][64][K] -> P[kz][n][64], split-bf16 MFMA.
// Per-wave 64x64 tile, 4 waves/block stacked in M (BM=256). No LDS, no
// barriers: each wave loads its own A rows from global (each element exactly
// once chip-wide), converts in-register (cvt_pk), B hi/lo stays L2-resident.
__global__ __launch_bounds__(256) void gemm1_mfma_k(
    const float* __restrict__ A, const unsigned short* __restrict__ Bt,
    float* __restrict__ P, int n, int K, int kchunk) {
    const int tid = threadIdx.x;
    const int lane = tid & 63;
    const int wid = tid >> 6;
    const int lrow = lane & 15, lkh = lane >> 4;
    const int wrow = blockIdx.x * 256 + wid * 64;  // wave's first output row
    const int k0 = blockIdx.y * kchunk;
    const int iters = kchunk / 32;  // K=16384, split 8 -> 64 (even)

    const unsigned short* Bh = Bt;
    const unsigned short* Bl = Bt + (size_t)64 * K;

    // per-lane base pointers (include lane's k-octet)
    const float* arow[4];
#pragma unroll
    for (int mf = 0; mf < 4; ++mf)
        arow[mf] = A + (size_t)(wrow + mf * 16 + lrow) * K + k0 + lkh * 8;
    const unsigned short* brow[4];
#pragma unroll
    for (int nf = 0; nf < 4; ++nf)
        brow[nf] = Bh + (size_t)(nf * 16 + lrow) * K + k0 + lkh * 8;
    const size_t loff = (size_t)64 * K;  // Bl - Bh

    f32x4 acc[4][4] = {};
    float4 stA[4][2], stB[4][2];

    auto issueA = [&](float4 (&st)[4][2], int kt) {
#pragma unroll
        for (int mf = 0; mf < 4; ++mf) {
            st[mf][0] = *(const float4*)(arow[mf] + kt * 32);
            st[mf][1] = *(const float4*)(arow[mf] + kt * 32 + 4);
        }
    };

    auto step = [&](float4 (&st)[4][2], int kt) {
        // B fragments for this step (L2-hot)
        bf16x8 bh[4], bl[4];
#pragma unroll
        for (int nf = 0; nf < 4; ++nf) {
            bh[nf] = *(const bf16x8*)(brow[nf] + kt * 32);
            bl[nf] = *(const bf16x8*)(brow[nf] + kt * 32 + loff);
        }
        // convert staged A regs -> hi/lo bf16 fragments (6 VALU / 2 elems)
        bf16x8 ah[4], al[4];
#pragma unroll
        for (int mf = 0; mf < 4; ++mf) {
            float f[8] = {st[mf][0].x, st[mf][0].y, st[mf][0].z, st[mf][0].w,
                          st[mf][1].x, st[mf][1].y, st[mf][1].z, st[mf][1].w};
            PK4 ph, pl;
#pragma unroll
            for (int j = 0; j < 4; ++j) {
                unsigned h = cvt_pk_bf16(f[2 * j], f[2 * j + 1]);
                float r0 = f[2 * j]     - __uint_as_float(h << 16);
                float r1 = f[2 * j + 1] - __uint_as_float(h & 0xFFFF0000u);
                ph.u[j] = h;
                pl.u[j] = cvt_pk_bf16(r0, r1);
            }
            ah[mf] = ph.v;
            al[mf] = pl.v;
        }
        // A regs now free: issue loads 2 steps ahead (hide under MFMA)
        if (kt + 2 < iters) issueA(st, kt + 2);
#pragma unroll
        for (int mf = 0; mf < 4; ++mf)
#pragma unroll
            for (int nf = 0; nf < 4; ++nf) {
                acc[mf][nf] = __builtin_amdgcn_mfma_f32_16x16x32_bf16(ah[mf], bh[nf], acc[mf][nf], 0, 0, 0);
                acc[mf][nf] = __builtin_amdgcn_mfma_f32_16x16x32_bf16(al[mf], bh[nf], acc[mf][nf], 0, 0, 0);
                acc[mf][nf] = __builtin_amdgcn_mfma_f32_16x16x32_bf16(ah[mf], bl[nf], acc[mf][nf], 0, 0, 0);
            }
    };

    issueA(stA, 0);
    issueA(stB, 1);
    for (int kt = 0; kt < iters; kt += 2) {
        step(stA, kt);
        step(stB, kt + 1);
    }

    // C/D layout: col = lane&15 (N), row = (lane>>4)*4 + reg (M)
    float* out = P + (size_t)blockIdx.y * n * 64;
#pragma unroll
    for (int mf = 0; mf < 4; ++mf)
#pragma unroll
        for (int nf = 0; nf < 4; ++nf)
#pragma unroll
            for (int j = 0; j < 4; ++j) {
                int row = wrow + mf * 16 + lkh * 4 + j;
                int col = nf * 16 + lrow;
                out[(size_t)row * 64 + col] = acc[mf][nf][j];
            }
}

__global__ void reduce8_k(float4* __restrict__ p, size_t q) {
    size_t i = (size_t)blockIdx.x * blockDim.x + threadIdx.x;
    if (i >= q) return;
    float4 a = p[i];
#pragma unroll
    for (int z = 1; z < 8; ++z) {
        float4 b = p[i + (size_t)z * q];
        a.x += b.x; a.y += b.y; a.z += b.z; a.w += b.w;
    }
    p[i] = a;
}

// --- propagate, float4 per thread: out[i,:] = sum_e w_e*h[src_e,:] + dis^2*h[i,:] + b
template <int F, bool RELU>
__global__ void prop_k(const float* __restrict__ h, const int* __restrict__ offs,
                       const int* __restrict__ src, const float* __restrict__ w,
                       const float* __restrict__ dis, const float* __restrict__ b,
                       float* __restrict__ out, int n) {
    constexpr int LPN = F / 4;
    int t = blockIdx.x * blockDim.x + threadIdx.x;
    int node = t / LPN, q = t % LPN;
    if (node >= n) return;
    float4 acc = make_float4(0.f, 0.f, 0.f, 0.f);
    int p0 = offs[node], p1 = offs[node + 1];
    for (int p = p0; p < p1; ++p) {
        float ww = w[p];
        float4 hv = *(const float4*)(h + (size_t)src[p] * F + q * 4);
        acc.x = fmaf(ww, hv.x, acc.x);
        acc.y = fmaf(ww, hv.y, acc.y);
        acc.z = fmaf(ww, hv.z, acc.z);
        acc.w = fmaf(ww, hv.w, acc.w);
    }
    float d = dis[node];
    float ds = d * d;
    float4 hv = *(const float4*)(h + (size_t)node * F + q * 4);
    float4 bv = *(const float4*)(b + q * 4);
    acc.x = fmaf(ds, hv.x, acc.x) + bv.x;
    acc.y = fmaf(ds, hv.y, acc.y) + bv.y;
    acc.z = fmaf(ds, hv.z, acc.z) + bv.z;
    acc.w = fmaf(ds, hv.w, acc.w) + bv.w;
    if (RELU) {
        acc.x = fmaxf(acc.x, 0.f);
        acc.y = fmaxf(acc.y, 0.f);
        acc.z = fmaxf(acc.z, 0.f);
        acc.w = fmaxf(acc.w, 0.f);
    }
    *(float4*)(out + (size_t)node * F + q * 4) = acc;
}

template <int K, int FO>
__global__ void gemm_small_k(const float* __restrict__ h, const float* __restrict__ W,
                             float* __restrict__ out, int n) {
    __shared__ float Ws[K * FO];
    for (int i = threadIdx.x; i < K * FO; i += blockDim.x) Ws[i] = W[i];
    __syncthreads();
    int t = blockIdx.x * blockDim.x + threadIdx.x;
    int node = t / FO, c = t % FO;
    if (node >= n) return;
    const float4* h4 = (const float4*)(h + (size_t)node * K);
    float acc = 0.f;
#pragma unroll
    for (int k4 = 0; k4 < K / 4; ++k4) {
        float4 v = h4[k4];
        acc = fmaf(v.x, Ws[(k4 * 4 + 0) * FO + c], acc);
        acc = fmaf(v.y, Ws[(k4 * 4 + 1) * FO + c], acc);
        acc = fmaf(v.z, Ws[(k4 * 4 + 2) * FO + c], acc);
        acc = fmaf(v.w, Ws[(k4 * 4 + 3) * FO + c], acc);
    }
    out[t] = acc;
}

// --- final propagate (F=16) + bias + softmax, float4/thread, 4 lanes/node
__global__ void prop_softmax_k(const float* __restrict__ h, const int* __restrict__ offs,
                               const int* __restrict__ src, const float* __restrict__ w,
                               const float* __restrict__ dis, const float* __restrict__ b,
                               float* __restrict__ out, int n) {
    int t = blockIdx.x * blockDim.x + threadIdx.x;
    int node = t >> 2, q = t & 3;
    if (node >= n) return;
    float4 acc = make_float4(0.f, 0.f, 0.f, 0.f);
    int p0 = offs[node], p1 = offs[node + 1];
    for (int p = p0; p < p1; ++p) {
        float ww = w[p];
        float4 hv = *(const float4*)(h + (size_t)src[p] * 16 + q * 4);
        acc.x = fmaf(ww, hv.x, acc.x);
        acc.y = fmaf(ww, hv.y, acc.y);
        acc.z = fmaf(ww, hv.z, acc.z);
        acc.w = fmaf(ww, hv.w, acc.w);
    }
    float d = dis[node];
    float ds = d * d;
    float4 hv = *(const float4*)(h + (size_t)node * 16 + q * 4);
    float4 bv = *(const float4*)(b + q * 4);
    acc.x = fmaf(ds, hv.x, acc.x) + bv.x;
    acc.y = fmaf(ds, hv.y, acc.y) + bv.y;
    acc.z = fmaf(ds, hv.z, acc.z) + bv.z;
    acc.w = fmaf(ds, hv.w, acc.w) + bv.w;
    float m = fmaxf(fmaxf(acc.x, acc.y), fmaxf(acc.z, acc.w));
    m = fmaxf(m, __shfl_xor(m, 1));
    m = fmaxf(m, __shfl_xor(m, 2));
    float4 e;
    e.x = __expf(acc.x - m);
    e.y = __expf(acc.y - m);
    e.z = __expf(acc.z - m);
    e.w = __expf(acc.w - m);
    float s = e.x + e.y + e.z + e.w;
    s += __shfl_xor(s, 1);
    s += __shfl_xor(s, 2);
    float inv = 1.f / s;
    e.x *= inv; e.y *= inv; e.z *= inv; e.w *= inv;
    *(float4*)(out + (size_t)node * 16 + q * 4) = e;
}

extern "C" void kernel_launch(void* const* d_in, const int* in_sizes, int n_in,
                              void* d_out, int out_size, void* d_ws, size_t ws_size,
                              hipStream_t stream) {
    const float* x  = (const float*)d_in[0];
    const int*   ei = (const int*)d_in[1];
    const float* W1 = (const float*)d_in[2];
    const float* b1 = (const float*)d_in[3];
    const float* W2 = (const float*)d_in[4];
    const float* b2 = (const float*)d_in[5];
    const float* W3 = (const float*)d_in[6];
    const float* b3 = (const float*)d_in[7];
    float* out = (float*)d_out;

    const int n = in_sizes[2] / 64;
    const int K = in_sizes[0] / n;
    const int E = in_sizes[1] / 2;

    char* ws = (char*)d_ws;
    size_t off = 0;
    auto alloc = [&](size_t bytes) {
        char* p = ws + off;
        off = (off + bytes + 255) & ~(size_t)255;
        return p;
    };
    int*   flag   = (int*)  alloc(4);
    int*   cnt    = (int*)  alloc((size_t)n * 4);
    int*   cursor = (int*)  alloc((size_t)n * 4);
    int*   offs   = (int*)  alloc((size_t)(n + 1) * 4);
    float* dis    = (float*)alloc((size_t)n * 4);
    int*   csrs   = (int*)  alloc((size_t)E * 4);
    float* csrw   = (float*)alloc((size_t)E * 4);
    unsigned short* Btw = (unsigned short*)alloc((size_t)2 * 64 * K * 2);
    float* P      = (float*)alloc((size_t)8 * n * 64 * 4);  // partials; plane 0 = H0
    float* H1     = (float*)alloc((size_t)n * 64 * 4);
    float* H2a    = (float*)alloc((size_t)n * 32 * 4);
    float* H2     = (float*)alloc((size_t)n * 32 * 4);
    float* H3a    = (float*)alloc((size_t)n * 16 * 4);
    (void)ws_size; (void)n_in; (void)out_size;

    init_k<<<(n + 255) / 256, 256, 0, stream>>>(ei, flag, cnt, n);
    count_deg_k<<<(E + 255) / 256, 256, 0, stream>>>(ei, E, flag, cnt);
    scan_k<<<1, 1024, 0, stream>>>(cnt, offs, dis, cursor, n);
    fill_csr_k<<<(E + 255) / 256, 256, 0, stream>>>(ei, E, flag, offs, cursor, dis, csrs, csrw);
    prep_w1_k<<<(K * 64 + 255) / 256, 256, 0, stream>>>(W1, Btw, K);

    dim3 g1(n / 256, 8);
    gemm1_mfma_k<<<g1, 256, 0, stream>>>(x, Btw, P, n, K, K / 8);
    size_t q = (size_t)n * 64 / 4;
    reduce8_k<<<(int)((q + 255) / 256), 256, 0, stream>>>((float4*)P, q);

    prop_k<64, true><<<(n * 16 + 255) / 256, 256, 0, stream>>>(P, offs, csrs, csrw, dis, b1, H1, n);
    gemm_small_k<64, 32><<<(n * 32 + 255) / 256, 256, 0, stream>>>(H1, W2, H2a, n);
    prop_k<32, true><<<(n * 8 + 255) / 256, 256, 0, stream>>>(H2a, offs, csrs, csrw, dis, b2, H2, n);
    gemm_small_k<32, 16><<<(n * 16 + 255) / 256, 256, 0, stream>>>(H2, W3, H3a, n);
    prop_softmax_k<<<(n * 4 + 255) / 256, 256, 0, stream>>>(H3a, offs, csrs, csrw, dis, b3, out, n);
}

// Round 5
// 416.548 us; speedup vs baseline: 1.2710x; 1.2710x over previous
//
#include <hip/hip_runtime.h>

// ---------------------------------------------------------------------------
// 3-layer GCN (PyG gcn_norm semantics) on MI355X.
//   0. init: zero cnt + detect edge_index storage (int32 vs int64)
//   1. degree count ; scan -> CSR offsets (+dis, +cursor=0) ; fill CSR
//   2. W1 -> split bf16 hi/lo + transpose (Bt[2][64][K])
//   3. H0 = x @ W1 split-bf16 MFMA (xh*Wh + xl*Wh + xh*Wl), K-split x4.
//      A streamed with NON-TEMPORAL loads so the 1 GB stream doesn't evict
//      the 4 MB B matrix from per-XCD L2 (B-thrash was R2-R4's limiter).
//      XCD-grouped grid swizzle keeps one K-chunk's B (2 MB) per XCD.
//   4. H1 = relu(Agg(H0)+b1) ; H2 = relu(Agg(H1@W2)+b2)
//   5. out = softmax(Agg(H2@W3)+b3)
// ---------------------------------------------------------------------------

typedef __attribute__((ext_vector_type(8))) short bf16x8;
typedef __attribute__((ext_vector_type(4))) float f32x4;
typedef __attribute__((ext_vector_type(4))) float fv4;

__device__ __forceinline__ float4 ldnt4(const float* p) {
    fv4 v = __builtin_nontemporal_load((const fv4*)p);
    return make_float4(v.x, v.y, v.z, v.w);
}
__device__ __forceinline__ void stnt(float* p, float v) {
    __builtin_nontemporal_store(v, p);
}

__device__ __forceinline__ unsigned cvt_pk_bf16(float a, float b) {
    // D[15:0] = bf16_rne(a), D[31:16] = bf16_rne(b)
    unsigned r;
    asm("v_cvt_pk_bf16_f32 %0, %1, %2" : "=v"(r) : "v"(a), "v"(b));
    return r;
}

__device__ __forceinline__ unsigned short f2bf_rne(float f) {
    unsigned u = __float_as_uint(f);
    unsigned r = (u + 0x7FFFu + ((u >> 16) & 1u)) >> 16;
    return (unsigned short)r;
}

// --- zero cnt; thread 0 probes int64-vs-int32 (int64 < 2^31 -> odd words 0)
__global__ void init_k(const int* __restrict__ ei, int* __restrict__ flag,
                       int* __restrict__ cnt, int n) {
    int t = blockIdx.x * blockDim.x + threadIdx.x;
    if (t < n) cnt[t] = 0;
    if (t == 0) {
        int f = 1;
        for (int i = 0; i < 256; ++i) {
            if (ei[2 * i + 1] != 0) { f = 0; break; }
        }
        *flag = f;
    }
}

__device__ __forceinline__ int edge_val(const int* __restrict__ ei, long long idx, int f64) {
    return f64 ? ei[2 * idx] : ei[(int)idx];
}

__global__ void count_deg_k(const int* __restrict__ ei, int E, const int* __restrict__ flag,
                            int* __restrict__ cnt) {
    int e = blockIdx.x * blockDim.x + threadIdx.x;
    if (e >= E) return;
    int f = *flag;
    int c = edge_val(ei, (long long)E + e, f);
    atomicAdd(&cnt[c], 1);
}

// scan + dis + cursor init, single block
__global__ void scan_k(const int* __restrict__ cnt, int* __restrict__ offs,
                       float* __restrict__ dis, int* __restrict__ cursor, int n) {
    __shared__ int sums[1024];
    const int t = threadIdx.x;
    const int base = t * 16;
    int loc[16];
    int s = 0;
#pragma unroll
    for (int i = 0; i < 16; ++i) {
        loc[i] = s;
        int idx = base + i;
        s += (idx < n) ? cnt[idx] : 0;
    }
    sums[t] = s;
    __syncthreads();
    for (int o = 1; o < 1024; o <<= 1) {
        int v = (t >= o) ? sums[t - o] : 0;
        __syncthreads();
        sums[t] += v;
        __syncthreads();
    }
    int tbase = (t == 0) ? 0 : sums[t - 1];
#pragma unroll
    for (int i = 0; i < 16; ++i) {
        int idx = base + i;
        if (idx < n) {
            offs[idx] = tbase + loc[i];
            cursor[idx] = 0;
            dis[idx] = rsqrtf((float)(cnt[idx] + 1));  // +1: self loop
        }
    }
    if (t == 1023) offs[n] = sums[1023];
}

__global__ void fill_csr_k(const int* __restrict__ ei, int E, const int* __restrict__ flag,
                           const int* __restrict__ offs, int* __restrict__ cursor,
                           const float* __restrict__ dis, int* __restrict__ src,
                           float* __restrict__ w) {
    int e = blockIdx.x * blockDim.x + threadIdx.x;
    if (e >= E) return;
    int f = *flag;
    int r = edge_val(ei, (long long)e, f);
    int c = edge_val(ei, (long long)E + e, f);
    int pos = offs[c] + atomicAdd(&cursor[c], 1);
    src[pos] = r;
    w[pos] = dis[r] * dis[c];
}

// --- W1 [K][64] fp32 -> Bt[2][64][K] bf16 (hi, lo), transposed.
__global__ void prep_w1_k(const float* __restrict__ W1, unsigned short* __restrict__ Bt,
                          int K) {
    int g = blockIdx.x * blockDim.x + threadIdx.x;
    if (g >= K * 64) return;
    int nn = g & 63, k = g >> 6;
    float f = W1[(size_t)k * 64 + nn];
    unsigned short hi = f2bf_rne(f);
    float hf = __uint_as_float((unsigned)hi << 16);
    unsigned short lo = f2bf_rne(f - hf);
    Bt[(size_t)nn * K + k] = hi;
    Bt[(size_t)64 * K + (size_t)nn * K + k] = lo;
}

// --- GEMM1: [n x K] fp32 @ Bt[2][64][K] -> P[kz][n][64], split-bf16 MFMA.
// BM=128, BN=64, BK=32, 256 thr = 4 waves (2m x 2n), wave tile 64x32.
// K-split x4. A loads NT (bypass L2), B loads cached (L2-resident per XCD).
__global__ __launch_bounds__(256) void gemm1_mfma_k(
    const float* __restrict__ A, const unsigned short* __restrict__ Bt,
    float* __restrict__ P, int n, int K, int kchunk) {
    __shared__ unsigned short As[2][128][40];  // [hi/lo][row][k], pad 40
    const int tid = threadIdx.x;
    const int lane = tid & 63;
    const int wid = tid >> 6;
    const int wm = wid >> 1, wn = wid & 1;
    const int lrow = lane & 15, lkh = lane >> 4;
    // XCD-grouped swizzle: XCD pair {2y,2y+1} owns K-chunk y -> its 2MB of B
    const int bid = blockIdx.x;
    const int by = (bid & 7) >> 1;
    const int bx = ((bid >> 3) << 1) | (bid & 1);
    const int bm = bx * 128;
    const int k0 = by * kchunk;
    const int iters = kchunk / 32;  // K=16384 /4 /32 = 128

    const unsigned short* Bh = Bt;
    const unsigned short* Bl = Bt + (size_t)64 * K;

    f32x4 acc[4][2] = {};
    float4 st[4];

    auto loadA = [&](int kt) {
#pragma unroll
        for (int i = 0; i < 4; ++i) {
            int v = tid + i * 256;
            int r = v >> 3, c = (v & 7) * 4;
            st[i] = ldnt4(A + (size_t)(bm + r) * K + k0 + kt * 32 + c);
        }
    };

    loadA(0);
    for (int kt = 0; kt < iters; ++kt) {
        // B fragments from global (L2-resident; NOT nt)
        bf16x8 bh[2], bl[2];
#pragma unroll
        for (int nf = 0; nf < 2; ++nf) {
            int brow = wn * 32 + nf * 16 + lrow;
            size_t bo = (size_t)brow * K + k0 + kt * 32 + lkh * 8;
            bh[nf] = *(const bf16x8*)(Bh + bo);
            bl[nf] = *(const bf16x8*)(Bl + bo);
        }
        // convert staged A regs -> hi/lo bf16 -> LDS (cvt_pk: 6 VALU / 2 elem)
#pragma unroll
        for (int i = 0; i < 4; ++i) {
            int v = tid + i * 256;
            int r = v >> 3, c = (v & 7) * 4;
            float f0 = st[i].x, f1 = st[i].y, f2 = st[i].z, f3 = st[i].w;
            unsigned h01 = cvt_pk_bf16(f0, f1);
            unsigned h23 = cvt_pk_bf16(f2, f3);
            float r0 = f0 - __uint_as_float(h01 << 16);
            float r1 = f1 - __uint_as_float(h01 & 0xFFFF0000u);
            float r2 = f2 - __uint_as_float(h23 << 16);
            float r3 = f3 - __uint_as_float(h23 & 0xFFFF0000u);
            unsigned l01 = cvt_pk_bf16(r0, r1);
            unsigned l23 = cvt_pk_bf16(r2, r3);
            *(uint2*)&As[0][r][c] = make_uint2(h01, h23);
            *(uint2*)&As[1][r][c] = make_uint2(l01, l23);
        }
        __syncthreads();
        if (kt + 1 < iters) loadA(kt + 1);  // prefetch under MFMA
        bf16x8 ah[4], al[4];
#pragma unroll
        for (int mf = 0; mf < 4; ++mf) {
            int row = wm * 64 + mf * 16 + lrow;
            ah[mf] = *(const bf16x8*)&As[0][row][lkh * 8];
            al[mf] = *(const bf16x8*)&As[1][row][lkh * 8];
        }
#pragma unroll
        for (int mf = 0; mf < 4; ++mf)
#pragma unroll
            for (int nf = 0; nf < 2; ++nf) {
                acc[mf][nf] = __builtin_amdgcn_mfma_f32_16x16x32_bf16(ah[mf], bh[nf], acc[mf][nf], 0, 0, 0);
                acc[mf][nf] = __builtin_amdgcn_mfma_f32_16x16x32_bf16(al[mf], bh[nf], acc[mf][nf], 0, 0, 0);
                acc[mf][nf] = __builtin_amdgcn_mfma_f32_16x16x32_bf16(ah[mf], bl[nf], acc[mf][nf], 0, 0, 0);
            }
        __syncthreads();
    }
    // C/D layout: col = lane&15, row = (lane>>4)*4 + reg. NT stores (read once).
    float* out = P + (size_t)by * n * 64;
#pragma unroll
    for (int mf = 0; mf < 4; ++mf)
#pragma unroll
        for (int nf = 0; nf < 2; ++nf)
#pragma unroll
            for (int j = 0; j < 4; ++j) {
                int row = bm + wm * 64 + mf * 16 + lkh * 4 + j;
                int col = wn * 32 + nf * 16 + lrow;
                stnt(out + (size_t)row * 64 + col, acc[mf][nf][j]);
            }
}

__global__ void reduce4_k(float4* __restrict__ p, size_t q) {
    size_t i = (size_t)blockIdx.x * blockDim.x + threadIdx.x;
    if (i >= q) return;
    float4 a = p[i];
#pragma unroll
    for (int z = 1; z < 4; ++z) {
        float4 b = ldnt4((const float*)(p + i + (size_t)z * q));
        a.x += b.x; a.y += b.y; a.z += b.z; a.w += b.w;
    }
    p[i] = a;
}

// --- propagate, float4 per thread: out[i,:] = sum_e w_e*h[src_e,:] + dis^2*h[i,:] + b
template <int F, bool RELU>
__global__ void prop_k(const float* __restrict__ h, const int* __restrict__ offs,
                       const int* __restrict__ src, const float* __restrict__ w,
                       const float* __restrict__ dis, const float* __restrict__ b,
                       float* __restrict__ out, int n) {
    constexpr int LPN = F / 4;
    int t = blockIdx.x * blockDim.x + threadIdx.x;
    int node = t / LPN, q = t % LPN;
    if (node >= n) return;
    float4 acc = make_float4(0.f, 0.f, 0.f, 0.f);
    int p0 = offs[node], p1 = offs[node + 1];
    for (int p = p0; p < p1; ++p) {
        float ww = w[p];
        float4 hv = *(const float4*)(h + (size_t)src[p] * F + q * 4);
        acc.x = fmaf(ww, hv.x, acc.x);
        acc.y = fmaf(ww, hv.y, acc.y);
        acc.z = fmaf(ww, hv.z, acc.z);
        acc.w = fmaf(ww, hv.w, acc.w);
    }
    float d = dis[node];
    float ds = d * d;
    float4 hv = *(const float4*)(h + (size_t)node * F + q * 4);
    float4 bv = *(const float4*)(b + q * 4);
    acc.x = fmaf(ds, hv.x, acc.x) + bv.x;
    acc.y = fmaf(ds, hv.y, acc.y) + bv.y;
    acc.z = fmaf(ds, hv.z, acc.z) + bv.z;
    acc.w = fmaf(ds, hv.w, acc.w) + bv.w;
    if (RELU) {
        acc.x = fmaxf(acc.x, 0.f);
        acc.y = fmaxf(acc.y, 0.f);
        acc.z = fmaxf(acc.z, 0.f);
        acc.w = fmaxf(acc.w, 0.f);
    }
    *(float4*)(out + (size_t)node * F + q * 4) = acc;
}

template <int K, int FO>
__global__ void gemm_small_k(const float* __restrict__ h, const float* __restrict__ W,
                             float* __restrict__ out, int n) {
    __shared__ float Ws[K * FO];
    for (int i = threadIdx.x; i < K * FO; i += blockDim.x) Ws[i] = W[i];
    __syncthreads();
    int t = blockIdx.x * blockDim.x + threadIdx.x;
    int node = t / FO, c = t % FO;
    if (node >= n) return;
    const float4* h4 = (const float4*)(h + (size_t)node * K);
    float acc = 0.f;
#pragma unroll
    for (int k4 = 0; k4 < K / 4; ++k4) {
        float4 v = h4[k4];
        acc = fmaf(v.x, Ws[(k4 * 4 + 0) * FO + c], acc);
        acc = fmaf(v.y, Ws[(k4 * 4 + 1) * FO + c], acc);
        acc = fmaf(v.z, Ws[(k4 * 4 + 2) * FO + c], acc);
        acc = fmaf(v.w, Ws[(k4 * 4 + 3) * FO + c], acc);
    }
    out[t] = acc;
}

// --- final propagate (F=16) + bias + softmax, float4/thread, 4 lanes/node
__global__ void prop_softmax_k(const float* __restrict__ h, const int* __restrict__ offs,
                               const int* __restrict__ src, const float* __restrict__ w,
                               const float* __restrict__ dis, const float* __restrict__ b,
                               float* __restrict__ out, int n) {
    int t = blockIdx.x * blockDim.x + threadIdx.x;
    int node = t >> 2, q = t & 3;
    if (node >= n) return;
    float4 acc = make_float4(0.f, 0.f, 0.f, 0.f);
    int p0 = offs[node], p1 = offs[node + 1];
    for (int p = p0; p < p1; ++p) {
        float ww = w[p];
        float4 hv = *(const float4*)(h + (size_t)src[p] * 16 + q * 4);
        acc.x = fmaf(ww, hv.x, acc.x);
        acc.y = fmaf(ww, hv.y, acc.y);
        acc.z = fmaf(ww, hv.z, acc.z);
        acc.w = fmaf(ww, hv.w, acc.w);
    }
    float d = dis[node];
    float ds = d * d;
    float4 hv = *(const float4*)(h + (size_t)node * 16 + q * 4);
    float4 bv = *(const float4*)(b + q * 4);
    acc.x = fmaf(ds, hv.x, acc.x) + bv.x;
    acc.y = fmaf(ds, hv.y, acc.y) + bv.y;
    acc.z = fmaf(ds, hv.z, acc.z) + bv.z;
    acc.w = fmaf(ds, hv.w, acc.w) + bv.w;
    float m = fmaxf(fmaxf(acc.x, acc.y), fmaxf(acc.z, acc.w));
    m = fmaxf(m, __shfl_xor(m, 1));
    m = fmaxf(m, __shfl_xor(m, 2));
    float4 e;
    e.x = __expf(acc.x - m);
    e.y = __expf(acc.y - m);
    e.z = __expf(acc.z - m);
    e.w = __expf(acc.w - m);
    float s = e.x + e.y + e.z + e.w;
    s += __shfl_xor(s, 1);
    s += __shfl_xor(s, 2);
    float inv = 1.f / s;
    e.x *= inv; e.y *= inv; e.z *= inv; e.w *= inv;
    *(float4*)(out + (size_t)node * 16 + q * 4) = e;
}

extern "C" void kernel_launch(void* const* d_in, const int* in_sizes, int n_in,
                              void* d_out, int out_size, void* d_ws, size_t ws_size,
                              hipStream_t stream) {
    const float* x  = (const float*)d_in[0];
    const int*   ei = (const int*)d_in[1];
    const float* W1 = (const float*)d_in[2];
    const float* b1 = (const float*)d_in[3];
    const float* W2 = (const float*)d_in[4];
    const float* b2 = (const float*)d_in[5];
    const float* W3 = (const float*)d_in[6];
    const float* b3 = (const float*)d_in[7];
    float* out = (float*)d_out;

    const int n = in_sizes[2] / 64;
    const int K = in_sizes[0] / n;
    const int E = in_sizes[1] / 2;

    char* ws = (char*)d_ws;
    size_t off = 0;
    auto alloc = [&](size_t bytes) {
        char* p = ws + off;
        off = (off + bytes + 255) & ~(size_t)255;
        return p;
    };
    int*   flag   = (int*)  alloc(4);
    int*   cnt    = (int*)  alloc((size_t)n * 4);
    int*   cursor = (int*)  alloc((size_t)n * 4);
    int*   offs   = (int*)  alloc((size_t)(n + 1) * 4);
    float* dis    = (float*)alloc((size_t)n * 4);
    int*   csrs   = (int*)  alloc((size_t)E * 4);
    float* csrw   = (float*)alloc((size_t)E * 4);
    unsigned short* Btw = (unsigned short*)alloc((size_t)2 * 64 * K * 2);
    float* P      = (float*)alloc((size_t)4 * n * 64 * 4);  // partials; plane 0 = H0
    float* H1     = (float*)alloc((size_t)n * 64 * 4);
    float* H2a    = (float*)alloc((size_t)n * 32 * 4);
    float* H2     = (float*)alloc((size_t)n * 32 * 4);
    float* H3a    = (float*)alloc((size_t)n * 16 * 4);
    (void)ws_size; (void)n_in; (void)out_size;

    init_k<<<(n + 255) / 256, 256, 0, stream>>>(ei, flag, cnt, n);
    count_deg_k<<<(E + 255) / 256, 256, 0, stream>>>(ei, E, flag, cnt);
    scan_k<<<1, 1024, 0, stream>>>(cnt, offs, dis, cursor, n);
    fill_csr_k<<<(E + 255) / 256, 256, 0, stream>>>(ei, E, flag, offs, cursor, dis, csrs, csrw);
    prep_w1_k<<<(K * 64 + 255) / 256, 256, 0, stream>>>(W1, Btw, K);

    gemm1_mfma_k<<<(n / 128) * 4, 256, 0, stream>>>(x, Btw, P, n, K, K / 4);
    size_t q = (size_t)n * 64 / 4;
    reduce4_k<<<(int)((q + 255) / 256), 256, 0, stream>>>((float4*)P, q);

    prop_k<64, true><<<(n * 16 + 255) / 256, 256, 0, stream>>>(P, offs, csrs, csrw, dis, b1, H1, n);
    gemm_small_k<64, 32><<<(n * 32 + 255) / 256, 256, 0, stream>>>(H1, W2, H2a, n);
    prop_k<32, true><<<(n * 8 + 255) / 256, 256, 0, stream>>>(H2a, offs, csrs, csrw, dis, b2, H2, n);
    gemm_small_k<32, 16><<<(n * 16 + 255) / 256, 256, 0, stream>>>(H2, W3, H3a, n);
    prop_softmax_k<<<(n * 4 + 255) / 256, 256, 0, stream>>>(H3a, offs, csrs, csrw, dis, b3, out, n);
}